// Round 6
// baseline (351.006 us; speedup 1.0000x reference)
//
#include <hip/hip_runtime.h>
#include <math.h>

// Problem constants: N=500000, NFEAT=64, K=8, HK=64
constexpr int NS    = 500000;
constexpr int NF    = 64;
constexpr int KG    = 8;
constexpr int HKC   = 64;
constexpr int NCELL = KG * HKC;           // 512 histogram cells
constexpr int NBLK  = (NS + 255) / 256;   // 1954 phase-A blocks (256 rows each)

typedef __attribute__((ext_vector_type(8))) _Float16 half8;
typedef __attribute__((ext_vector_type(4))) float f32x4;

// xor-16 within 32-lane halves: ds_swizzle BitMode offset 0x401F
__device__ __forceinline__ float swz16_f(float v) {
    return __int_as_float(__builtin_amdgcn_ds_swizzle(__float_as_int(v), 0x401F));
}
__device__ __forceinline__ int swz16_i(int v) {
    return __builtin_amdgcn_ds_swizzle(v, 0x401F);
}

// Kernel 1: w = exp(z) (fp32) split into fp16 hi/lo pair; zero the A region.
__global__ void prep_kernel(const float* __restrict__ z,
                            _Float16* __restrict__ w_hi,
                            _Float16* __restrict__ w_lo,
                            float* __restrict__ A) {
    int i = blockIdx.x * blockDim.x + threadIdx.x;
    if (i < KG * HKC * NF) {
        float w = expf(z[i]);
        _Float16 h = (_Float16)w;           // RNE
        w_hi[i] = h;
        w_lo[i] = (_Float16)(w - (float)h); // residual: ~2^-22 total pair error
    }
    if (i < NCELL) A[i] = 0.0f;
}

// Main kernel, transposed-C orientation: mfma(A=w, B=x) so that per lane
// col(lane&15)=x-row and row(q*4+reg)=w-col — each lane holds 16 w-cols of ONE
// x-row -> argmax is in-lane (cheap) instead of cross-lane DPP chains (R5).
// MFMAs issued in 3 independent passes (hh, lh, hl) — no dependent-issue
// stalls (R5's 16.8 cyc/MFMA vs 4.8 µbench was the A,A,A dependent triplets).
template <bool PRIV>
__global__ __launch_bounds__(256, 2) void monn_mfma_kernel(
    const float* __restrict__ x,
    const _Float16* __restrict__ w_hi,
    const _Float16* __restrict__ w_lo,
    const float* __restrict__ t,
    float* __restrict__ y,
    float* __restrict__ dest) {   // PRIV ? partial buffer : global A

    __shared__ unsigned lhist[NCELL];
    if (PRIV) {
        for (int i = threadIdx.x; i < NCELL; i += 256) lhist[i] = 0u;
        __syncthreads();
    }

    const int lane = threadIdx.x & 63;
    const int wave = blockIdx.x * 4 + (threadIdx.x >> 6);
    const long base = (long)wave * 64;
    const int m  = lane & 15;
    const int q  = lane >> 4;
    const int q4 = q * 4;
    const int a32 = ((lane ^ 32) << 2);   // ds_bpermute byte-addr for xor-32

    if (base < NS) {   // wave-uniform predicate: barriers + swizzles stay whole-wave
        // --- Load 64 x rows and split to fp16 hi/lo fragments (B-operand layout:
        //     B[k=q*8+j][n=lane&15] — identical addressing to the A layout) ---
        float4 xv[4][2][2];
#pragma unroll
        for (int rt = 0; rt < 4; ++rt) {
            long row = base + rt * 16 + m;
            if (row >= NS) row = NS - 1;      // tail clamp; outputs guarded below
            const float* xp = x + row * NF;
#pragma unroll
            for (int s = 0; s < 2; ++s) {
                const int k0 = s * 32 + q * 8;
                xv[rt][s][0] = *reinterpret_cast<const float4*>(xp + k0);
                xv[rt][s][1] = *reinterpret_cast<const float4*>(xp + k0 + 4);
            }
        }
        half8 Xh[4][2], Xl[4][2];
#pragma unroll
        for (int rt = 0; rt < 4; ++rt)
#pragma unroll
            for (int s = 0; s < 2; ++s) {
                const float f[8] = {xv[rt][s][0].x, xv[rt][s][0].y, xv[rt][s][0].z, xv[rt][s][0].w,
                                    xv[rt][s][1].x, xv[rt][s][1].y, xv[rt][s][1].z, xv[rt][s][1].w};
#pragma unroll
                for (int j = 0; j < 8; ++j) {
                    _Float16 h = (_Float16)f[j];
                    Xh[rt][s][j] = h;
                    Xl[rt][s][j] = (_Float16)(f[j] - (float)h);
                }
            }

        float ymin[4];
        int   code[4];
#pragma unroll
        for (int rt = 0; rt < 4; ++rt) { ymin[rt] = INFINITY; code[rt] = 0; }

        for (int g = 0; g < KG; ++g) {
            // bias for this group's w-cols, folded into acc init (per-lane:
            // w-col = c*16 + q*4 + j -> float4 at t + g*64 + c*16 + q4). L1-hot.
            f32x4 acc[4][4];   // [c (w Mtile)][rt (x Ntile)]
#pragma unroll
            for (int c = 0; c < 4; ++c) {
                const float4 tv = *reinterpret_cast<const float4*>(t + g * HKC + c * 16 + q4);
                const f32x4 tin = (f32x4){tv.x, tv.y, tv.z, tv.w};
#pragma unroll
                for (int rt = 0; rt < 4; ++rt) acc[c][rt] = tin;
            }

#pragma unroll
            for (int s = 0; s < 2; ++s) {
                // batch all 8 w loads (A-operand layout A[m=lane&15][k=q*8+j])
                half8 Wh[4], Wl[4];
#pragma unroll
                for (int c = 0; c < 4; ++c) {
                    const size_t off = (size_t)(g * HKC + c * 16 + m) * NF + s * 32 + q * 8;
                    Wh[c] = *reinterpret_cast<const half8*>(w_hi + off);
                    Wl[c] = *reinterpret_cast<const half8*>(w_lo + off);
                }
                // pass 1: wh*xh — 16 independent MFMAs
#pragma unroll
                for (int c = 0; c < 4; ++c)
#pragma unroll
                    for (int rt = 0; rt < 4; ++rt)
                        acc[c][rt] = __builtin_amdgcn_mfma_f32_16x16x32_f16(Wh[c], Xh[rt][s], acc[c][rt], 0, 0, 0);
                // pass 2: wl*xh
#pragma unroll
                for (int c = 0; c < 4; ++c)
#pragma unroll
                    for (int rt = 0; rt < 4; ++rt)
                        acc[c][rt] = __builtin_amdgcn_mfma_f32_16x16x32_f16(Wl[c], Xh[rt][s], acc[c][rt], 0, 0, 0);
                // pass 3: wh*xl
#pragma unroll
                for (int c = 0; c < 4; ++c)
#pragma unroll
                    for (int rt = 0; rt < 4; ++rt)
                        acc[c][rt] = __builtin_amdgcn_mfma_f32_16x16x32_f16(Wh[c], Xl[rt][s], acc[c][rt], 0, 0, 0);
            }

            // --- epilogue: per x-row argmax over this group's 64 w-cols ---
#pragma unroll
            for (int rt = 0; rt < 4; ++rt) {
                // in-lane max over 16 values (balanced tree; compiler fuses max3)
                float t01 = fmaxf(acc[0][rt][0], acc[0][rt][1]);
                float t23 = fmaxf(acc[0][rt][2], acc[0][rt][3]);
                float t45 = fmaxf(acc[1][rt][0], acc[1][rt][1]);
                float t67 = fmaxf(acc[1][rt][2], acc[1][rt][3]);
                float t89 = fmaxf(acc[2][rt][0], acc[2][rt][1]);
                float tab = fmaxf(acc[2][rt][2], acc[2][rt][3]);
                float tcd = fmaxf(acc[3][rt][0], acc[3][rt][1]);
                float tef = fmaxf(acc[3][rt][2], acc[3][rt][3]);
                float v = fmaxf(fmaxf(fmaxf(t01, t23), fmaxf(t45, t67)),
                                fmaxf(fmaxf(t89, tab), fmaxf(tcd, tef)));
                // equality scan, descending w-col (c desc, j desc): last write =
                // smallest wc -> jnp.argmax first-occurrence semantics.
                // candidates c*16+j are inline consts; q4 bits are disjoint.
                int h = 0;
#pragma unroll
                for (int c = 3; c >= 0; --c)
#pragma unroll
                    for (int j = 3; j >= 0; --j)
                        h = (acc[c][rt][j] == v) ? (c * 16 + j) : h;
                h |= q4;
                // cross-q combine (4 lanes, stride 16): xor16 via ds_swizzle,
                // xor32 via ds_bpermute; tie -> smaller h (first occurrence)
                {
                    float v2 = swz16_f(v);
                    int   h2 = swz16_i(h);
                    bool take = (v2 > v) || (v2 == v && h2 < h);
                    v = take ? v2 : v;  h = take ? h2 : h;
                    float v3 = __int_as_float(__builtin_amdgcn_ds_bpermute(a32, __float_as_int(v)));
                    int   h3 = __builtin_amdgcn_ds_bpermute(a32, h);
                    take = (v3 > v) || (v3 == v && h3 < h);
                    v = take ? v3 : v;  h = take ? h3 : h;
                }
                // running min over groups: strict < keeps first (lowest g)
                const bool better = v < ymin[rt];
                ymin[rt] = fminf(ymin[rt], v);
                code[rt] = better ? ((g << 6) | h) : code[rt];
            }
        }

        // q==0 lanes (16) write y (contiguous 64B per rt) and bump histogram
        if (q == 0) {
#pragma unroll
            for (int rt = 0; rt < 4; ++rt) {
                const long row = base + rt * 16 + m;
                if (row < NS) {
                    y[row] = ymin[rt];
                    if (PRIV) atomicAdd(&lhist[code[rt]], 1u);       // LDS, banked
                    else      atomicAdd(&dest[code[rt]], 1.0f);      // fallback
                }
            }
        }
    }

    if (PRIV) {
        __syncthreads();
        // plain coalesced stores of this block's 512-cell histogram
        float* p = dest + (size_t)blockIdx.x * NCELL;
        for (int i = threadIdx.x; i < NCELL; i += 256) p[i] = (float)lhist[i];
    }
}

// Phase B: A[c] = sum_b partial[b][c]. 16384 atomics onto 512 cells — negligible.
__global__ void reduce_kernel(const float* __restrict__ partial, float* __restrict__ A) {
    const int tid = blockIdx.x * blockDim.x + threadIdx.x;   // 0..16383
    const int c = tid & (NCELL - 1);
    const int s = tid >> 9;                                  // 0..31
    float sum = 0.0f;
    for (int b = s; b < NBLK; b += 32)                       // coalesced across lanes
        sum += partial[(size_t)b * NCELL + c];
    atomicAdd(&A[c], sum);
}

extern "C" void kernel_launch(void* const* d_in, const int* in_sizes, int n_in,
                              void* d_out, int out_size, void* d_ws, size_t ws_size,
                              hipStream_t stream) {
    const float* x = (const float*)d_in[0];  // [NS, NF]
    const float* z = (const float*)d_in[1];  // [KG, HKC, NF]
    const float* t = (const float*)d_in[2];  // [KG, HKC]

    float* y = (float*)d_out;        // [NS]
    float* A = (float*)d_out + NS;   // [NCELL]

    _Float16* w_hi = (_Float16*)d_ws;                          // 64 KB
    _Float16* w_lo = w_hi + (size_t)KG * HKC * NF;             // 64 KB
    float* partial = (float*)((char*)d_ws + 2 * sizeof(_Float16) * KG * HKC * NF);

    const size_t need = 2 * sizeof(_Float16) * KG * HKC * NF
                      + (size_t)NBLK * NCELL * sizeof(float);  // ~4.13 MB

    const int prep_elems = KG * HKC * NF;
    prep_kernel<<<(prep_elems + 255) / 256, 256, 0, stream>>>(z, w_hi, w_lo, A);

    if (ws_size >= need) {
        monn_mfma_kernel<true><<<NBLK, 256, 0, stream>>>(x, w_hi, w_lo, t, y, partial);
        reduce_kernel<<<64, 256, 0, stream>>>(partial, A);
    } else {
        monn_mfma_kernel<false><<<NBLK, 256, 0, stream>>>(x, w_hi, w_lo, t, y, A);
    }
}